// Round 2
// baseline (3655.762 us; speedup 1.0000x reference)
//
#include <hip/hip_runtime.h>
#include <cstdint>
#include <cstring>
#include <cmath>

constexpr int kH    = 16;
constexpr int kL    = 24;
constexpr int kS    = 4096;
constexpr int kEOS  = 129;
constexpr float kSCALE = 0.125f;   // 1/sqrt(64)
constexpr int kNS   = 32;          // attention splits
constexpr int kTOK  = kS / kNS;    // 128 tokens per split

struct Params {
  const float *x, *kc, *vc, *ln1g, *Wq, *Wk, *Wv, *Wo, *ln2g, *Wg, *Wu, *Wd, *lnfg;
  const float *h1w1, *h1b1, *h1w2, *h1b2, *h1w3, *h1b3;
  const float *h2w1, *h2b1, *h2w2, *h2b2, *h2w3, *h2b3;
  const float *h3w1, *h3b1, *h3w2, *h3b2, *h3w3, *h3b3;
  const float *c1emb, *c2emb;
  float *hA, *hB, *qkvp, *part, *gup, *t2p, *cat, *out;
  unsigned *bar;
  float G[30];
};

// ---------------- reduction helpers ----------------

__device__ __forceinline__ float wave_sum(float v) {
  v += __shfl_xor(v, 32, 64); v += __shfl_xor(v, 16, 64);
  v += __shfl_xor(v, 8, 64);  v += __shfl_xor(v, 4, 64);
  v += __shfl_xor(v, 2, 64);  v += __shfl_xor(v, 1, 64);
  return v;
}
__device__ __forceinline__ float wave_max(float v) {
  v = fmaxf(v, __shfl_xor(v, 32, 64)); v = fmaxf(v, __shfl_xor(v, 16, 64));
  v = fmaxf(v, __shfl_xor(v, 8, 64));  v = fmaxf(v, __shfl_xor(v, 4, 64));
  v = fmaxf(v, __shfl_xor(v, 2, 64));  v = fmaxf(v, __shfl_xor(v, 1, 64));
  return v;
}
__device__ __forceinline__ float block_sum4(float v, float* red) {
  v = wave_sum(v);
  if ((threadIdx.x & 63) == 0) red[threadIdx.x >> 6] = v;
  __syncthreads();
  float s = red[0] + red[1] + red[2] + red[3];
  __syncthreads();
  return s;
}
__device__ __forceinline__ float block_max4(float v, float* red) {
  v = wave_max(v);
  if ((threadIdx.x & 63) == 0) red[threadIdx.x >> 6] = v;
  __syncthreads();
  float s = fmaxf(fmaxf(red[0], red[1]), fmaxf(red[2], red[3]));
  __syncthreads();
  return s;
}

__device__ __forceinline__ void ln_stats(const float* __restrict__ h, float* red,
                                         float& mean, float& rs) {
  int tid = threadIdx.x;
  float v0 = h[tid], v1 = h[tid + 256], v2 = h[tid + 512], v3 = h[tid + 768];
  float s = block_sum4(v0 + v1 + v2 + v3, red);
  mean = s * (1.0f / 1024.0f);
  float d0 = v0 - mean, d1 = v1 - mean, d2 = v2 - mean, d3 = v3 - mean;
  float sq = block_sum4(d0 * d0 + d1 * d1 + d2 * d2 + d3 * d3, red);
  rs = 1.0f / sqrtf(sq * (1.0f / 1024.0f) + 1e-5f);
}

__device__ __forceinline__ float gelu_f(float x) {
  float t = tanhf(0.7978845608028654f * (x + 0.044715f * x * x * x));
  return 0.5f * x * (1.0f + t);
}

// device-scope grid barrier (cooperative launch => all blocks resident).
// release on arrival (L2 writeback), relaxed agent-scope spin, acquire on exit.
__device__ __forceinline__ void gbar(unsigned* cnt, unsigned target) {
  __syncthreads();
  if (threadIdx.x == 0) {
    __hip_atomic_fetch_add(cnt, 1u, __ATOMIC_RELEASE, __HIP_MEMORY_SCOPE_AGENT);
    while (__hip_atomic_load(cnt, __ATOMIC_RELAXED, __HIP_MEMORY_SCOPE_AGENT) < target)
      __builtin_amdgcn_s_sleep(2);
    __threadfence();   // acquire: invalidate stale L1/L2 before post-barrier reads
  }
  __syncthreads();
}

// ---------------- the whole forward pass, one kernel ----------------

__global__ __launch_bounds__(256, 2) void k_all(Params p) {
  const int tid = threadIdx.x;
  const unsigned NB = gridDim.x;
  unsigned nbar = 0;
  auto GBAR = [&]() { nbar += 1u; gbar(p.bar, nbar * NB); };

  __shared__ float4 sh4[256];
  __shared__ float xs[64];
  __shared__ float red4[4];
  __shared__ float4 q4[16], kn4[16], vn4[16];
  __shared__ float sc[132];
  __shared__ float osh[64];
  __shared__ int ish;

  for (int l = 0; l < kL; ++l) {
    const float* h_in = l ? p.hA : p.x;
    const float* ln1  = p.ln1g + (size_t)l * 1024;
    const float* ln2  = p.ln2g + (size_t)l * 1024;
    const float* Wq_l = p.Wq + (size_t)l * 1024 * 1024;
    const float* Wk_l = p.Wk + (size_t)l * 1024 * 1024;
    const float* Wv_l = p.Wv + (size_t)l * 1024 * 1024;
    const float* Wo_l = p.Wo + (size_t)l * 1024 * 1024;
    const float* Wg_l = p.Wg + (size_t)l * 1024 * 4096;
    const float* Wu_l = p.Wu + (size_t)l * 1024 * 4096;
    const float* Wd_l = p.Wd + (size_t)l * 4096 * 1024;
    const float* Kc_l = p.kc + (size_t)l * kS * 1024;
    const float* Vc_l = p.vc + (size_t)l * kS * 1024;

    // ---- phase A: LN1 + QKV split-K partials (192 vblocks = 12 x 16)
    for (unsigned vb = blockIdx.x; vb < 192u; vb += NB) {
      int bx = (int)(vb % 12u), by = (int)(vb / 12u);
      __syncthreads();
      float mean, rs;
      ln_stats(h_in, red4, mean, rs);
      int rb = by * 64;
      if (tid < 64) xs[tid] = (h_in[rb + tid] - mean) * rs * ln1[rb + tid];
      if (bx == 0 && tid < 64) p.hB[rb + tid] = h_in[rb + tid];
      __syncthreads();
      int c4 = tid & 63, w = tid >> 6;
      int vcol4 = bx * 64 + c4;
      int mat = vcol4 >> 8;
      const float4* W4 = reinterpret_cast<const float4*>(
          (mat == 0) ? Wq_l : ((mat == 1) ? Wk_l : Wv_l));
      int wcol4 = vcol4 & 255;
      float4 acc = {0.f, 0.f, 0.f, 0.f};
      int r0 = w * 16;
      #pragma unroll
      for (int i = 0; i < 16; ++i) {
        float xv = xs[r0 + i];
        float4 wv = W4[(size_t)(rb + r0 + i) * 256 + wcol4];
        acc.x += xv * wv.x; acc.y += xv * wv.y; acc.z += xv * wv.z; acc.w += xv * wv.w;
      }
      sh4[tid] = acc;
      __syncthreads();
      if (tid < 64) {
        float4 a = sh4[tid], b = sh4[tid + 64], c = sh4[tid + 128], d = sh4[tid + 192];
        a.x += b.x + c.x + d.x; a.y += b.y + c.y + d.y;
        a.z += b.z + c.z + d.z; a.w += b.w + c.w + d.w;
        reinterpret_cast<float4*>(p.qkvp)[(size_t)by * 768 + bx * 64 + tid] = a;
      }
    }
    GBAR();

    // ---- phase B: attention partials (512 vblocks = 32 splits x 16 heads)
    for (unsigned vb = blockIdx.x; vb < 512u; vb += NB) {
      int split = (int)(vb & 31u), head = (int)(vb >> 5);
      __syncthreads();
      if (tid < 64) {
        float s = 0.f;
        #pragma unroll
        for (int pp = 0; pp < 16; ++pp) s += p.qkvp[pp * 3072 + head * 64 + tid];
        ((float*)q4)[tid] = s;
      } else if (tid < 128) {
        int d = tid - 64; float s = 0.f;
        #pragma unroll
        for (int pp = 0; pp < 16; ++pp) s += p.qkvp[pp * 3072 + 1024 + head * 64 + d];
        ((float*)kn4)[d] = s;
      } else if (tid < 192) {
        int d = tid - 128; float s = 0.f;
        #pragma unroll
        for (int pp = 0; pp < 16; ++pp) s += p.qkvp[pp * 3072 + 2048 + head * 64 + d];
        ((float*)vn4)[d] = s;
      }
      __syncthreads();
      int base = split * kTOK;
      int count = kTOK + (split == kNS - 1 ? 1 : 0);
      int wv = tid >> 6, lane = tid & 63, grp = lane >> 4, l16 = lane & 15;
      float4 qf = q4[l16];
      for (int t = wv * 4 + grp; t < count; t += 16) {
        float4 kf = (t < kTOK)
          ? reinterpret_cast<const float4*>(Kc_l + (size_t)(base + t) * 1024 + head * 64)[l16]
          : kn4[l16];
        float d = qf.x * kf.x + qf.y * kf.y + qf.z * kf.z + qf.w * kf.w;
        d += __shfl_xor(d, 1, 16); d += __shfl_xor(d, 2, 16);
        d += __shfl_xor(d, 4, 16); d += __shfl_xor(d, 8, 16);
        if (l16 == 0) sc[t] = d * kSCALE;
      }
      __syncthreads();
      float v = (tid < count) ? sc[tid] : -1e30f;
      float m = block_max4(v, red4);
      float pexp = 0.f;
      if (tid < count) { pexp = expf(sc[tid] - m); sc[tid] = pexp; }
      float lsum = block_sum4(pexp, red4);
      float4 acc = {0.f, 0.f, 0.f, 0.f};
      for (int t = wv * 4 + grp; t < count; t += 16) {
        float4 vf = (t < kTOK)
          ? reinterpret_cast<const float4*>(Vc_l + (size_t)(base + t) * 1024 + head * 64)[l16]
          : vn4[l16];
        float pw = sc[t];
        acc.x += pw * vf.x; acc.y += pw * vf.y; acc.z += pw * vf.z; acc.w += pw * vf.w;
      }
      // reduce 16 token-groups per dim-quad via shared
      sh4[(wv * 4 + grp) * 16 + l16] = acc;
      __syncthreads();
      float* pp = &p.part[(size_t)(head * kNS + split) * 68];
      if (tid < 16) {
        float4 s = sh4[tid];
        #pragma unroll
        for (int k = 1; k < 16; ++k) {
          float4 b = sh4[k * 16 + tid];
          s.x += b.x; s.y += b.y; s.z += b.z; s.w += b.w;
        }
        reinterpret_cast<float4*>(pp + 4)[tid] = s;
      }
      if (tid == 0) { pp[0] = m; pp[1] = lsum; }
    }
    GBAR();

    // ---- phase C: combine splits + Wo gemv (256 vblocks = 16 colblk x 16 heads)
    for (unsigned vb = blockIdx.x; vb < 256u; vb += NB) {
      int bx = (int)(vb & 15u), head = (int)(vb >> 4);
      __syncthreads();
      if (tid < 64) {
        const float* pp = p.part + (size_t)(head * kNS) * 68;
        float m = -1e30f;
        for (int s = 0; s < kNS; ++s) m = fmaxf(m, pp[s * 68]);
        float lsum = 0.f, acc = 0.f;
        for (int s = 0; s < kNS; ++s) {
          float e = expf(pp[s * 68] - m);
          lsum += e * pp[s * 68 + 1];
          acc  += e * pp[s * 68 + 4 + tid];
        }
        osh[tid] = acc / lsum;
      }
      __syncthreads();
      int c4 = tid & 15, w = tid >> 4;
      int vcol4 = bx * 16 + c4;
      const float4* W4 = reinterpret_cast<const float4*>(Wo_l);
      float4 acc = {0.f, 0.f, 0.f, 0.f};
      int r0 = w * 4;
      #pragma unroll
      for (int i = 0; i < 4; ++i) {
        int r = r0 + i;
        float xv = osh[r];
        float4 wv = W4[(size_t)(head * 64 + r) * 256 + vcol4];
        acc.x += xv * wv.x; acc.y += xv * wv.y; acc.z += xv * wv.z; acc.w += xv * wv.w;
      }
      sh4[tid] = acc;
      __syncthreads();
      if (tid < 16) {
        float4 a = sh4[tid];
        #pragma unroll
        for (int k = 1; k < 16; ++k) {
          float4 b = sh4[k * 16 + tid];
          a.x += b.x; a.y += b.y; a.z += b.z; a.w += b.w;
        }
        int vcol = (bx * 16 + tid) * 4;
        atomicAdd(&p.hB[vcol],     a.x);
        atomicAdd(&p.hB[vcol + 1], a.y);
        atomicAdd(&p.hB[vcol + 2], a.z);
        atomicAdd(&p.hB[vcol + 3], a.w);
      }
    }
    GBAR();

    // ---- phase D: LN2 + [Wg|Wu] split-K partials (512 vblocks = 32 x 16)
    for (unsigned vb = blockIdx.x; vb < 512u; vb += NB) {
      int bx = (int)(vb & 31u), by = (int)(vb >> 5);
      __syncthreads();
      float mean, rs;
      ln_stats(p.hB, red4, mean, rs);
      int rb = by * 64;
      if (tid < 64) xs[tid] = (p.hB[rb + tid] - mean) * rs * ln2[rb + tid];
      if (bx == 0 && tid < 64) p.hA[rb + tid] = p.hB[rb + tid];
      __syncthreads();
      int c4 = tid & 63, w = tid >> 6;
      int vcol4 = bx * 64 + c4;
      int mat = vcol4 >> 10;
      const float4* W4 = reinterpret_cast<const float4*>(mat ? Wu_l : Wg_l);
      int wcol4 = vcol4 & 1023;
      float4 acc = {0.f, 0.f, 0.f, 0.f};
      int r0 = w * 16;
      #pragma unroll
      for (int i = 0; i < 16; ++i) {
        float xv = xs[r0 + i];
        float4 wv = W4[(size_t)(rb + r0 + i) * 1024 + wcol4];
        acc.x += xv * wv.x; acc.y += xv * wv.y; acc.z += xv * wv.z; acc.w += xv * wv.w;
      }
      sh4[tid] = acc;
      __syncthreads();
      if (tid < 64) {
        float4 a = sh4[tid], b = sh4[tid + 64], c = sh4[tid + 128], d = sh4[tid + 192];
        a.x += b.x + c.x + d.x; a.y += b.y + c.y + d.y;
        a.z += b.z + c.z + d.z; a.w += b.w + c.w + d.w;
        reinterpret_cast<float4*>(p.gup)[(size_t)by * 2048 + bx * 64 + tid] = a;
      }
    }
    GBAR();

    // ---- phase E: act + Wd (256 vblocks = 4 x 64)
    for (unsigned vb = blockIdx.x; vb < 256u; vb += NB) {
      int bx = (int)(vb & 3u), by = (int)(vb >> 2);
      __syncthreads();
      int rb = by * 64;
      if (tid < 64) {
        float gs = 0.f, us = 0.f;
        #pragma unroll
        for (int pp = 0; pp < 16; ++pp) {
          gs += p.gup[pp * 8192 + rb + tid];
          us += p.gup[pp * 8192 + 4096 + rb + tid];
        }
        xs[tid] = gelu_f(gs) * us;
      }
      __syncthreads();
      int c4 = tid & 63, w = tid >> 6;
      int vcol4 = bx * 64 + c4;
      const float4* W4 = reinterpret_cast<const float4*>(Wd_l);
      float4 acc = {0.f, 0.f, 0.f, 0.f};
      int r0 = w * 16;
      #pragma unroll
      for (int i = 0; i < 16; ++i) {
        float xv = xs[r0 + i];
        float4 wv = W4[(size_t)(rb + r0 + i) * 256 + vcol4];
        acc.x += xv * wv.x; acc.y += xv * wv.y; acc.z += xv * wv.z; acc.w += xv * wv.w;
      }
      sh4[tid] = acc;
      __syncthreads();
      if (tid < 64) {
        float4 a = sh4[tid], b = sh4[tid + 64], c = sh4[tid + 128], d = sh4[tid + 192];
        a.x += b.x + c.x + d.x; a.y += b.y + c.y + d.y;
        a.z += b.z + c.z + d.z; a.w += b.w + c.w + d.w;
        int vcol = (bx * 64 + tid) * 4;
        atomicAdd(&p.hA[vcol],     a.x);
        atomicAdd(&p.hA[vcol + 1], a.y);
        atomicAdd(&p.hA[vcol + 2], a.z);
        atomicAdd(&p.hA[vcol + 3], a.w);
      }
    }
    GBAR();
  }

  // ---- final LN -> cat[0:1024]
  if (blockIdx.x == 0) {
    float mean, rs;
    ln_stats(p.hA, red4, mean, rs);
    #pragma unroll
    for (int k = 0; k < 4; ++k) {
      int i = tid + 256 * k;
      p.cat[i] = (p.hA[i] - mean) * rs * p.lnfg[i];
    }
  }
  GBAR();

  // ---- three head stages
  const float* w1s[3] = {p.h1w1, p.h2w1, p.h3w1};
  const float* b1s[3] = {p.h1b1, p.h2b1, p.h3b1};
  const float* w2s[3] = {p.h1w2, p.h2w2, p.h3w2};
  const float* b2s[3] = {p.h1b2, p.h2b2, p.h3b2};
  const float* w3s[3] = {p.h1w3, p.h2w3, p.h3w3};
  const float* b3s[3] = {p.h1b3, p.h2b3, p.h3b3};
  float* t1p = p.gup;   // reuse FF partial buffer for head partials

  #pragma unroll
  for (int s = 0; s < 3; ++s) {
    const int ny = (s == 0) ? 16 : ((s == 1) ? 32 : 48);
    const int n3 = (s == 0) ? 130 : 128;
    float* logits = (s == 0) ? (p.out + 3) : ((s == 1) ? (p.out + 133) : (p.out + 261));
    const float* w1 = w1s[s]; const float* b1 = b1s[s];
    const float* w2 = w2s[s]; const float* b2 = b2s[s];
    const float* w3 = w3s[s]; const float* b3 = b3s[s];

    // g1: cat[0:ny*64] @ w1 -> t1p partials; (0,0) inits logits = b3
    for (unsigned vb = blockIdx.x; vb < (unsigned)(4 * ny); vb += NB) {
      int bx = (int)(vb & 3u), by = (int)(vb >> 2);
      __syncthreads();
      if (bx == 0 && by == 0 && tid < n3) logits[tid] = b3[tid];
      int c4 = tid & 63, w = tid >> 6;
      int vcol4 = bx * 64 + c4;
      const float4* W4 = reinterpret_cast<const float4*>(w1);
      float4 acc = {0.f, 0.f, 0.f, 0.f};
      int rb = by * 64, r0 = w * 16;
      #pragma unroll
      for (int i = 0; i < 16; ++i) {
        int r = rb + r0 + i;
        float xv = p.cat[r];
        float4 wv = W4[(size_t)r * 256 + vcol4];
        acc.x += xv * wv.x; acc.y += xv * wv.y; acc.z += xv * wv.z; acc.w += xv * wv.w;
      }
      sh4[tid] = acc;
      __syncthreads();
      if (tid < 64) {
        float4 a = sh4[tid], b = sh4[tid + 64], c = sh4[tid + 128], d = sh4[tid + 192];
        a.x += b.x + c.x + d.x; a.y += b.y + c.y + d.y;
        a.z += b.z + c.z + d.z; a.w += b.w + c.w + d.w;
        reinterpret_cast<float4*>(t1p)[(size_t)by * 256 + bx * 64 + tid] = a;
      }
    }
    GBAR();

    // g2: relu(b1 + sum t1p) @ w2 -> t2p partials (64 vblocks)
    for (unsigned vb = blockIdx.x; vb < 64u; vb += NB) {
      int bx = (int)(vb & 3u), by = (int)(vb >> 2);
      __syncthreads();
      int rb = by * 64;
      if (tid < 64) {
        float ssum = b1[rb + tid];
        for (int q = 0; q < ny; ++q) ssum += t1p[q * 1024 + rb + tid];
        xs[tid] = fmaxf(ssum, 0.f);
      }
      __syncthreads();
      int c4 = tid & 63, w = tid >> 6;
      int vcol4 = bx * 64 + c4;
      const float4* W4 = reinterpret_cast<const float4*>(w2);
      float4 acc = {0.f, 0.f, 0.f, 0.f};
      int r0 = w * 16;
      #pragma unroll
      for (int i = 0; i < 16; ++i) {
        float xv = xs[r0 + i];
        float4 wv = W4[(size_t)(rb + r0 + i) * 256 + vcol4];
        acc.x += xv * wv.x; acc.y += xv * wv.y; acc.z += xv * wv.z; acc.w += xv * wv.w;
      }
      sh4[tid] = acc;
      __syncthreads();
      if (tid < 64) {
        float4 a = sh4[tid], b = sh4[tid + 64], c = sh4[tid + 128], d = sh4[tid + 192];
        a.x += b.x + c.x + d.x; a.y += b.y + c.y + d.y;
        a.z += b.z + c.z + d.z; a.w += b.w + c.w + d.w;
        reinterpret_cast<float4*>(p.t2p)[(size_t)by * 256 + bx * 64 + tid] = a;
      }
    }
    GBAR();

    // g3: relu(b2 + sum t2p) @ w3 -> atomicAdd logits (16 vblocks)
    for (unsigned vb = blockIdx.x; vb < 16u; vb += NB) {
      __syncthreads();
      int rb = (int)vb * 64;
      if (tid < 64) {
        float ssum = b2[rb + tid];
        #pragma unroll
        for (int q = 0; q < 16; ++q) ssum += p.t2p[q * 1024 + rb + tid];
        xs[tid] = fmaxf(ssum, 0.f);
      }
      __syncthreads();
      if (tid < n3) {
        float acc = 0.f;
        for (int i = 0; i < 64; ++i) acc += xs[i] * w3[(size_t)(rb + i) * n3 + tid];
        atomicAdd(&logits[tid], acc);
      }
    }
    GBAR();

    // sample (block 0 only)
    if (blockIdx.x == 0) {
      const float* gb = p.G + s * 10;
      if (tid == 0) {
        float pr[130];
        float mx = -1e30f;
        for (int i = 0; i < n3; ++i) mx = fmaxf(mx, logits[i]);
        float ssum = 0.f;
        for (int i = 0; i < n3; ++i) { pr[i] = expf(logits[i] - mx); ssum += pr[i]; }
        for (int i = 0; i < n3; ++i) pr[i] /= ssum;
        float tp[10]; int ti[10];
        for (int k = 0; k < 10; ++k) {
          float best = -1.f; int bi = 0;
          for (int i = 0; i < n3; ++i)
            if (pr[i] > best) { best = pr[i]; bi = i; }
          tp[k] = best; ti[k] = bi; pr[bi] = -2.f;
        }
        int choice;
        if (s == 0) {
          int is_eos = (ti[0] == kEOS);
          float mp[10]; float msum = 0.f;
          for (int k = 0; k < 10; ++k) {
            mp[k] = tp[k] * ((ti[k] != kEOS) ? 1.f : 0.f);
            msum += mp[k];
          }
          float bestsc = -1e30f; int ba = 0;
          for (int k = 0; k < 10; ++k) {
            float scv = logf(mp[k] / msum + 1e-9f) + gb[k];
            if (scv > bestsc) { bestsc = scv; ba = k; }
          }
          choice = is_eos ? kEOS : ti[ba];
          p.out[2] = (float)choice;
        } else {
          float bestsc = -1e30f; int ba = 0;
          for (int k = 0; k < 10; ++k) {
            float scv = logf(tp[k] + 1e-9f) + gb[k];
            if (scv > bestsc) { bestsc = scv; ba = k; }
          }
          choice = ti[ba];
          if (s == 1) p.out[1] = (float)choice;
          else        p.out[0] = (float)choice;
        }
        ish = choice;
      }
      __syncthreads();
      if (s == 0) {
        int zi = ish; if (zi > 127) zi = 127;
        for (int i = tid; i < 1024; i += 256)
          p.cat[1024 + i] = p.c1emb[(size_t)zi * 1024 + i];
      } else if (s == 1) {
        int y = ish;
        for (int i = tid; i < 1024; i += 256)
          p.cat[2048 + i] = p.c2emb[(size_t)y * 1024 + i];
      }
    }
    GBAR();
  }
}

// ---------------- host: JAX threefry2x32 (partitionable) ----------------

static inline uint32_t rotl32(uint32_t x, uint32_t r) { return (x << r) | (x >> (32 - r)); }

static void threefry2x32(uint32_t k0, uint32_t k1, uint32_t x0, uint32_t x1,
                         uint32_t* o0, uint32_t* o1) {
  uint32_t ks0 = k0, ks1 = k1, ks2 = k0 ^ k1 ^ 0x1BD11BDAu;
  const uint32_t R0[4] = {13, 15, 26, 6};
  const uint32_t R1[4] = {17, 29, 16, 24};
  x0 += ks0; x1 += ks1;
  for (int j = 0; j < 4; ++j) { x0 += x1; x1 = rotl32(x1, R0[j]); x1 ^= x0; }
  x0 += ks1; x1 += ks2 + 1u;
  for (int j = 0; j < 4; ++j) { x0 += x1; x1 = rotl32(x1, R1[j]); x1 ^= x0; }
  x0 += ks2; x1 += ks0 + 2u;
  for (int j = 0; j < 4; ++j) { x0 += x1; x1 = rotl32(x1, R0[j]); x1 ^= x0; }
  x0 += ks0; x1 += ks1 + 3u;
  for (int j = 0; j < 4; ++j) { x0 += x1; x1 = rotl32(x1, R1[j]); x1 ^= x0; }
  x0 += ks1; x1 += ks2 + 4u;
  for (int j = 0; j < 4; ++j) { x0 += x1; x1 = rotl32(x1, R0[j]); x1 ^= x0; }
  x0 += ks2; x1 += ks0 + 5u;
  *o0 = x0; *o1 = x1;
}

static void gumbel10_part(uint32_t k0, uint32_t k1, float* g) {
  const float tiny = 1.1754943508222875e-38f;
  for (int i = 0; i < 10; ++i) {
    uint32_t a, c;
    threefry2x32(k0, k1, 0u, (uint32_t)i, &a, &c);
    uint32_t bits = a ^ c;
    uint32_t fb = (bits >> 9) | 0x3f800000u;
    float f; memcpy(&f, &fb, 4);
    f -= 1.0f;
    float u = f * (1.0f - tiny) + tiny;
    if (u < tiny) u = tiny;
    g[i] = -logf(-logf(u));
  }
}

// ---------------- entry ----------------

extern "C" void kernel_launch(void* const* d_in, const int* in_sizes, int n_in,
                              void* d_out, int out_size, void* d_ws, size_t ws_size,
                              hipStream_t stream) {
  (void)in_sizes; (void)n_in; (void)out_size; (void)ws_size;
  float* ws = (float*)d_ws;

  Params prm;
  prm.x    = (const float*)d_in[0];
  prm.kc   = (const float*)d_in[1];
  prm.vc   = (const float*)d_in[2];
  prm.ln1g = (const float*)d_in[3];
  prm.Wq   = (const float*)d_in[4];
  prm.Wk   = (const float*)d_in[5];
  prm.Wv   = (const float*)d_in[6];
  prm.Wo   = (const float*)d_in[7];
  prm.ln2g = (const float*)d_in[8];
  prm.Wg   = (const float*)d_in[9];
  prm.Wu   = (const float*)d_in[10];
  prm.Wd   = (const float*)d_in[11];
  prm.lnfg = (const float*)d_in[12];
  prm.h1w1 = (const float*)d_in[13]; prm.h1b1 = (const float*)d_in[14];
  prm.h1w2 = (const float*)d_in[15]; prm.h1b2 = (const float*)d_in[16];
  prm.h1w3 = (const float*)d_in[17]; prm.h1b3 = (const float*)d_in[18];
  prm.h2w1 = (const float*)d_in[19]; prm.h2b1 = (const float*)d_in[20];
  prm.h2w2 = (const float*)d_in[21]; prm.h2b2 = (const float*)d_in[22];
  prm.h2w3 = (const float*)d_in[23]; prm.h2b3 = (const float*)d_in[24];
  prm.h3w1 = (const float*)d_in[25]; prm.h3b1 = (const float*)d_in[26];
  prm.h3w2 = (const float*)d_in[27]; prm.h3b2 = (const float*)d_in[28];
  prm.h3w3 = (const float*)d_in[29]; prm.h3b3 = (const float*)d_in[30];
  prm.c1emb = (const float*)d_in[31];
  prm.c2emb = (const float*)d_in[32];

  prm.hA   = ws;                    // 1024
  prm.hB   = ws + 1024;             // 1024
  prm.qkvp = ws + 2048;             // 16*3072 = 49152
  prm.part = ws + 51200;            // 16*32*68 = 34816
  prm.gup  = ws + 86016;            // 16*8192 = 131072 (t1p alias in heads)
  prm.t2p  = ws + 86016 + 49152;    // 16*1024 (inside gup tail)
  prm.cat  = ws + 217088;           // 3072
  prm.out  = (float*)d_out;
  prm.bar  = (unsigned*)(ws + 220160);

  uint32_t k1a, k1b, k2a, k2b, k3a, k3b;
  threefry2x32(0u, 42u, 0u, 0u, &k1a, &k1b);
  threefry2x32(0u, 42u, 0u, 1u, &k2a, &k2b);
  threefry2x32(0u, 42u, 0u, 2u, &k3a, &k3b);
  gumbel10_part(k1a, k1b, prm.G);
  gumbel10_part(k2a, k2b, prm.G + 10);
  gumbel10_part(k3a, k3b, prm.G + 20);

  hipMemsetAsync(prm.bar, 0, sizeof(unsigned), stream);

  static int occ = -1;
  if (occ < 0) {
    int nb = 0;
    if (hipOccupancyMaxActiveBlocksPerMultiprocessor(&nb, k_all, 256, 0) != hipSuccess || nb < 1)
      nb = 1;
    occ = nb;
  }
  int nblk = 256 * (occ >= 2 ? 2 : 1);

  void* args[] = { &prm };
  hipLaunchCooperativeKernel(k_all, dim3(nblk), dim3(256), args, 0, stream);
}

// Round 3
// 3647.550 us; speedup vs baseline: 1.0023x; 1.0023x over previous
//
#include <hip/hip_runtime.h>
#include <cstdint>
#include <cstring>
#include <cmath>

constexpr int kEOS  = 129;
constexpr float kSCALE = 0.125f;   // 1/sqrt(64)

struct Params {
  const float *x, *kc, *vc, *ln1g, *Wq, *Wk, *Wv, *Wo, *ln2g, *Wg, *Wu, *Wd, *lnfg;
  const float *h1w1, *h1b1, *h1w2, *h1b2, *h1w3, *h1b3;
  const float *h2w1, *h2b1, *h2w2, *h2b2, *h2w3, *h2b3;
  const float *h3w1, *h3b1, *h3w2, *h3b2, *h3w3, *h3b3;
  const float *c1emb, *c2emb;
  float *hA, *hB, *qkvp, *part, *gup, *t2p, *catE, *out;
  unsigned *bar;
  float G[30];
};

// ---------------- reduction helpers ----------------

__device__ __forceinline__ float wave_sum(float v) {
  v += __shfl_xor(v, 32, 64); v += __shfl_xor(v, 16, 64);
  v += __shfl_xor(v, 8, 64);  v += __shfl_xor(v, 4, 64);
  v += __shfl_xor(v, 2, 64);  v += __shfl_xor(v, 1, 64);
  return v;
}
__device__ __forceinline__ float wave_max(float v) {
  v = fmaxf(v, __shfl_xor(v, 32, 64)); v = fmaxf(v, __shfl_xor(v, 16, 64));
  v = fmaxf(v, __shfl_xor(v, 8, 64));  v = fmaxf(v, __shfl_xor(v, 4, 64));
  v = fmaxf(v, __shfl_xor(v, 2, 64));  v = fmaxf(v, __shfl_xor(v, 1, 64));
  return v;
}
__device__ __forceinline__ float block_sum4(float v, float* red) {
  v = wave_sum(v);
  if ((threadIdx.x & 63) == 0) red[threadIdx.x >> 6] = v;
  __syncthreads();
  float s = red[0] + red[1] + red[2] + red[3];
  __syncthreads();
  return s;
}
__device__ __forceinline__ float block_max4(float v, float* red) {
  v = wave_max(v);
  if ((threadIdx.x & 63) == 0) red[threadIdx.x >> 6] = v;
  __syncthreads();
  float s = fmaxf(fmaxf(red[0], red[1]), fmaxf(red[2], red[3]));
  __syncthreads();
  return s;
}

__device__ __forceinline__ void ln_stats(const float* __restrict__ h, float* red,
                                         float& mean, float& rs) {
  int tid = threadIdx.x;
  float v0 = h[tid], v1 = h[tid + 256], v2 = h[tid + 512], v3 = h[tid + 768];
  float s = block_sum4(v0 + v1 + v2 + v3, red);
  mean = s * (1.0f / 1024.0f);
  float d0 = v0 - mean, d1 = v1 - mean, d2 = v2 - mean, d3 = v3 - mean;
  float sq = block_sum4(d0 * d0 + d1 * d1 + d2 * d2 + d3 * d3, red);
  rs = 1.0f / sqrtf(sq * (1.0f / 1024.0f) + 1e-5f);
}

__device__ __forceinline__ float gelu_f(float x) {
  float t = tanhf(0.7978845608028654f * (x + 0.044715f * x * x * x));
  return 0.5f * x * (1.0f + t);
}

// ---------------- the whole forward pass, one kernel ----------------

__global__ __launch_bounds__(256, 2) void k_all(Params p) {
  const int tid = threadIdx.x;
  const unsigned NB = gridDim.x;
  const unsigned bid = blockIdx.x;
  const bool pf = (NB == 512u);
  unsigned e = 0;

  __shared__ __align__(16) float Klds[128 * 68];   // 34816 B, stride-68 padded
  __shared__ float4 sh4[256];
  __shared__ float4 q4f[16], kn4f[16], vn4f[16];
  __shared__ float xs[64];
  __shared__ float red4[4];
  __shared__ float sc[132];
  __shared__ float osh[64];
  __shared__ int ish;

  // barrier arrays (cacheline-spaced)
  unsigned* leaf = p.bar;            // 64 lines
  unsigned* mid  = p.bar + 2048;     // 8 lines
  unsigned* root = p.bar + 2304;     // 1 line
  unsigned* flag = p.bar + 2336;     // 8 lines

  auto arrive = [&](unsigned ee) {
    __syncthreads();
    if (tid == 0) {
      unsigned perLeaf = NB >> 6;
      unsigned lid = bid & 63u;
      unsigned old = __hip_atomic_fetch_add(&leaf[lid * 32], 1u, __ATOMIC_ACQ_REL,
                                            __HIP_MEMORY_SCOPE_AGENT);
      if (old == ee * perLeaf - 1u) {
        unsigned mo = __hip_atomic_fetch_add(&mid[(lid & 7u) * 32], 1u, __ATOMIC_ACQ_REL,
                                             __HIP_MEMORY_SCOPE_AGENT);
        if (mo == ee * 8u - 1u) {
          unsigned ro = __hip_atomic_fetch_add(root, 1u, __ATOMIC_ACQ_REL,
                                               __HIP_MEMORY_SCOPE_AGENT);
          if (ro == ee * 8u - 1u) {
            #pragma unroll
            for (int g = 0; g < 8; ++g)
              __hip_atomic_store(&flag[g * 32], ee, __ATOMIC_RELEASE,
                                 __HIP_MEMORY_SCOPE_AGENT);
          }
        }
      }
    }
  };
  auto waitb = [&](unsigned ee) {
    if (tid == 0) {
      while (__hip_atomic_load(&flag[(bid & 7u) * 32], __ATOMIC_RELAXED,
                               __HIP_MEMORY_SCOPE_AGENT) < ee)
        __builtin_amdgcn_s_sleep(16);
      __threadfence();
    }
    __syncthreads();
  };

  // prefetch register files
  float4 wa[16];    // A weights (Wq|Wk|Wv frags)
  float4 wgu[16];   // D weights (Wg|Wu frags)
  float4 we[16];    // E weights (Wd frags)
  float4 vreg[8];   // B V-tile

  auto pfA = [&](const float* Wq_l, const float* Wk_l, const float* Wv_l, int bx, int by) {
    int c4 = tid & 63, w = tid >> 6;
    int vcol4 = bx * 64 + c4;
    int mat = vcol4 >> 8;
    const float4* W4 = (const float4*)((mat == 0) ? Wq_l : ((mat == 1) ? Wk_l : Wv_l));
    int wcol4 = vcol4 & 255, rb = by * 64, r0 = w * 16;
    #pragma unroll
    for (int i = 0; i < 16; ++i) wa[i] = W4[(size_t)(rb + r0 + i) * 256 + wcol4];
  };
  auto pfD = [&](const float* Wg_l, const float* Wu_l, int bx, int by) {
    int c4 = tid & 63, w = tid >> 6;
    int vcol4 = bx * 64 + c4;
    const float4* W4 = (const float4*)((vcol4 >> 10) ? Wu_l : Wg_l);
    int wcol4 = vcol4 & 1023, rb = by * 64, r0 = w * 16;
    #pragma unroll
    for (int i = 0; i < 16; ++i) wgu[i] = W4[(size_t)(rb + r0 + i) * 1024 + wcol4];
  };
  auto pfE = [&](const float* Wd_l, int bx, int by) {
    int c4 = tid & 63, w = tid >> 6;
    int vcol4 = bx * 64 + c4, rb = by * 64, r0 = w * 16;
    const float4* W4 = (const float4*)Wd_l;
    #pragma unroll
    for (int i = 0; i < 16; ++i) we[i] = W4[(size_t)(rb + r0 + i) * 256 + vcol4];
  };
  auto loadKV = [&](const float* Kc_l, const float* Vc_l, int split, int head) {
    __syncthreads();
    int base = split * 128;
    const float4* K4 = (const float4*)Kc_l;
    const float4* V4 = (const float4*)Vc_l;
    #pragma unroll
    for (int u = 0; u < 8; ++u) {
      int idx = tid + 256 * u;
      int t = idx >> 4, q = idx & 15;
      float4 kf = K4[(size_t)(base + t) * 256 + head * 16 + q];
      *(float4*)&Klds[t * 68 + q * 4] = kf;
    }
    int wv = tid >> 6, grp = (tid >> 4) & 3, l16 = tid & 15;
    int g0 = wv * 4 + grp;
    #pragma unroll
    for (int i = 0; i < 8; ++i) {
      int t = g0 + 16 * i;
      vreg[i] = V4[(size_t)(base + t) * 256 + head * 16 + l16];
    }
  };

  auto compB = [&](int split, int head) {
    if (tid < 64) {
      float s = 0.f;
      #pragma unroll
      for (int q = 0; q < 16; ++q) s += p.qkvp[q * 3072 + head * 64 + tid];
      ((float*)q4f)[tid] = s;
    } else if (tid < 128) {
      int d = tid - 64; float s = 0.f;
      #pragma unroll
      for (int q = 0; q < 16; ++q) s += p.qkvp[q * 3072 + 1024 + head * 64 + d];
      ((float*)kn4f)[d] = s;
    } else if (tid < 192) {
      int d = tid - 128; float s = 0.f;
      #pragma unroll
      for (int q = 0; q < 16; ++q) s += p.qkvp[q * 3072 + 2048 + head * 64 + d];
      ((float*)vn4f)[d] = s;
    }
    __syncthreads();
    bool last = (split == 31);
    int wv = tid >> 6, lane = tid & 63, grp = lane >> 4, l16 = lane & 15;
    int g0 = wv * 4 + grp;
    float4 qf = q4f[l16];
    #pragma unroll
    for (int i = 0; i < 8; ++i) {
      int t = g0 + 16 * i;
      float4 kf = *(float4*)&Klds[t * 68 + l16 * 4];
      float d = qf.x * kf.x + qf.y * kf.y + qf.z * kf.z + qf.w * kf.w;
      d += __shfl_xor(d, 1, 16); d += __shfl_xor(d, 2, 16);
      d += __shfl_xor(d, 4, 16); d += __shfl_xor(d, 8, 16);
      if (l16 == 0) sc[t] = d * kSCALE;
    }
    if (last && g0 == 0) {
      float4 kf = kn4f[l16];
      float d = qf.x * kf.x + qf.y * kf.y + qf.z * kf.z + qf.w * kf.w;
      d += __shfl_xor(d, 1, 16); d += __shfl_xor(d, 2, 16);
      d += __shfl_xor(d, 4, 16); d += __shfl_xor(d, 8, 16);
      if (l16 == 0) sc[128] = d * kSCALE;
    }
    __syncthreads();
    int count = last ? 129 : 128;
    float v = (tid < count) ? sc[tid] : -1e30f;
    float m = block_max4(v, red4);
    float pexp = 0.f;
    if (tid < count) { pexp = expf(sc[tid] - m); sc[tid] = pexp; }
    float lsum = block_sum4(pexp, red4);
    float4 acc = {0.f, 0.f, 0.f, 0.f};
    #pragma unroll
    for (int i = 0; i < 8; ++i) {
      int t = g0 + 16 * i;
      float pw = sc[t];
      acc.x += pw * vreg[i].x; acc.y += pw * vreg[i].y;
      acc.z += pw * vreg[i].z; acc.w += pw * vreg[i].w;
    }
    if (last && g0 == 0) {
      float pw = sc[128];
      float4 vf = vn4f[l16];
      acc.x += pw * vf.x; acc.y += pw * vf.y; acc.z += pw * vf.z; acc.w += pw * vf.w;
    }
    sh4[g0 * 16 + l16] = acc;
    __syncthreads();
    float* pp_ = &p.part[(size_t)(head * 32 + split) * 68];
    if (tid < 16) {
      float4 s = sh4[tid];
      #pragma unroll
      for (int k = 1; k < 16; ++k) {
        float4 b = sh4[k * 16 + tid];
        s.x += b.x; s.y += b.y; s.z += b.z; s.w += b.w;
      }
      ((float4*)(pp_ + 4))[tid] = s;
    }
    if (tid == 0) { pp_[0] = m; pp_[1] = lsum; }
  };

  // =================== layer loop ===================
  if (pf && bid < 192u) pfA(p.Wq, p.Wk, p.Wv, (int)(bid % 12u), (int)(bid / 12u));

  for (int l = 0; l < 24; ++l) {
    const float* h_in = l ? p.hA : p.x;
    const float* ln1  = p.ln1g + (size_t)l * 1024;
    const float* ln2  = p.ln2g + (size_t)l * 1024;
    const float* Wq_l = p.Wq + (size_t)l * 1048576;
    const float* Wk_l = p.Wk + (size_t)l * 1048576;
    const float* Wv_l = p.Wv + (size_t)l * 1048576;
    const float* Wo_l = p.Wo + (size_t)l * 1048576;
    const float* Wg_l = p.Wg + (size_t)l * 4194304;
    const float* Wu_l = p.Wu + (size_t)l * 4194304;
    const float* Wd_l = p.Wd + (size_t)l * 4194304;
    const float* Kc_l = p.kc + (size_t)l * 4096 * 1024;
    const float* Vc_l = p.vc + (size_t)l * 4096 * 1024;

    auto compA = [&](int bx, int by) {
      __syncthreads();
      float mean, rs;
      ln_stats(h_in, red4, mean, rs);
      int rb = by * 64;
      if (tid < 64) xs[tid] = (h_in[rb + tid] - mean) * rs * ln1[rb + tid];
      if (bx == 0 && tid < 64) p.hB[rb + tid] = h_in[rb + tid];
      __syncthreads();
      float4 acc = {0.f, 0.f, 0.f, 0.f};
      int r0 = (tid >> 6) * 16;
      #pragma unroll
      for (int i = 0; i < 16; ++i) {
        float xv = xs[r0 + i];
        acc.x += xv * wa[i].x; acc.y += xv * wa[i].y;
        acc.z += xv * wa[i].z; acc.w += xv * wa[i].w;
      }
      sh4[tid] = acc;
      __syncthreads();
      if (tid < 64) {
        float4 a = sh4[tid], b = sh4[tid + 64], c = sh4[tid + 128], d = sh4[tid + 192];
        a.x += b.x + c.x + d.x; a.y += b.y + c.y + d.y;
        a.z += b.z + c.z + d.z; a.w += b.w + c.w + d.w;
        ((float4*)p.qkvp)[(size_t)by * 768 + bx * 64 + tid] = a;
      }
    };
    auto compC = [&](int bx, int head) {
      __syncthreads();
      if (tid < 64) {
        const float* pp_ = p.part + (size_t)(head * 32) * 68;
        float m = -1e30f;
        for (int s = 0; s < 32; ++s) m = fmaxf(m, pp_[s * 68]);
        float lsum = 0.f, acc = 0.f;
        for (int s = 0; s < 32; ++s) {
          float e_ = expf(pp_[s * 68] - m);
          lsum += e_ * pp_[s * 68 + 1];
          acc  += e_ * pp_[s * 68 + 4 + tid];
        }
        osh[tid] = acc / lsum;
      }
      __syncthreads();
      int c4 = tid & 15, w = tid >> 4;
      int vcol4 = bx * 16 + c4;
      const float4* W4 = (const float4*)Wo_l;
      float4 acc = {0.f, 0.f, 0.f, 0.f};
      int r0 = w * 4;
      #pragma unroll
      for (int i = 0; i < 4; ++i) {
        float xv = osh[r0 + i];
        float4 wv = W4[(size_t)(head * 64 + r0 + i) * 256 + vcol4];
        acc.x += xv * wv.x; acc.y += xv * wv.y; acc.z += xv * wv.z; acc.w += xv * wv.w;
      }
      sh4[tid] = acc;
      __syncthreads();
      if (tid < 16) {
        float4 a = sh4[tid];
        #pragma unroll
        for (int k = 1; k < 16; ++k) {
          float4 b = sh4[k * 16 + tid];
          a.x += b.x; a.y += b.y; a.z += b.z; a.w += b.w;
        }
        int vcol = (bx * 16 + tid) * 4;
        atomicAdd(&p.hB[vcol],     a.x);
        atomicAdd(&p.hB[vcol + 1], a.y);
        atomicAdd(&p.hB[vcol + 2], a.z);
        atomicAdd(&p.hB[vcol + 3], a.w);
      }
    };
    auto compD = [&](int bx, int by) {
      __syncthreads();
      float mean, rs;
      ln_stats(p.hB, red4, mean, rs);
      int rb = by * 64;
      if (tid < 64) xs[tid] = (p.hB[rb + tid] - mean) * rs * ln2[rb + tid];
      if (bx == 0 && tid < 64) p.hA[rb + tid] = p.hB[rb + tid];
      __syncthreads();
      float4 acc = {0.f, 0.f, 0.f, 0.f};
      int r0 = (tid >> 6) * 16;
      #pragma unroll
      for (int i = 0; i < 16; ++i) {
        float xv = xs[r0 + i];
        acc.x += xv * wgu[i].x; acc.y += xv * wgu[i].y;
        acc.z += xv * wgu[i].z; acc.w += xv * wgu[i].w;
      }
      sh4[tid] = acc;
      __syncthreads();
      if (tid < 64) {
        float4 a = sh4[tid], b = sh4[tid + 64], c = sh4[tid + 128], d = sh4[tid + 192];
        a.x += b.x + c.x + d.x; a.y += b.y + c.y + d.y;
        a.z += b.z + c.z + d.z; a.w += b.w + c.w + d.w;
        ((float4*)p.gup)[(size_t)by * 2048 + bx * 64 + tid] = a;
      }
    };
    auto compE = [&](int bx, int by) {
      __syncthreads();
      int rb = by * 64;
      if (tid < 64) {
        float gs = 0.f, us = 0.f;
        #pragma unroll
        for (int q = 0; q < 16; ++q) {
          gs += p.gup[q * 8192 + rb + tid];
          us += p.gup[q * 8192 + 4096 + rb + tid];
        }
        xs[tid] = gelu_f(gs) * us;
      }
      __syncthreads();
      float4 acc = {0.f, 0.f, 0.f, 0.f};
      int r0 = (tid >> 6) * 16;
      #pragma unroll
      for (int i = 0; i < 16; ++i) {
        float xv = xs[r0 + i];
        acc.x += xv * we[i].x; acc.y += xv * we[i].y;
        acc.z += xv * we[i].z; acc.w += xv * we[i].w;
      }
      sh4[tid] = acc;
      __syncthreads();
      if (tid < 64) {
        float4 a = sh4[tid], b = sh4[tid + 64], c = sh4[tid + 128], d = sh4[tid + 192];
        a.x += b.x + c.x + d.x; a.y += b.y + c.y + d.y;
        a.z += b.z + c.z + d.z; a.w += b.w + c.w + d.w;
        int vcol = (bx * 64 + tid) * 4;
        atomicAdd(&p.hA[vcol],     a.x);
        atomicAdd(&p.hA[vcol + 1], a.y);
        atomicAdd(&p.hA[vcol + 2], a.z);
        atomicAdd(&p.hA[vcol + 3], a.w);
      }
    };

    // ---- A
    if (pf) { if (bid < 192u) compA((int)(bid % 12u), (int)(bid / 12u)); }
    else {
      for (unsigned vb = bid; vb < 192u; vb += NB) {
        int bx = (int)(vb % 12u), by = (int)(vb / 12u);
        pfA(Wq_l, Wk_l, Wv_l, bx, by); compA(bx, by);
      }
    }
    ++e; arrive(e);
    if (pf) loadKV(Kc_l, Vc_l, (int)(bid & 31u), (int)((bid >> 5) & 15u));
    waitb(e);
    // ---- B
    if (pf) compB((int)(bid & 31u), (int)((bid >> 5) & 15u));
    else {
      for (unsigned vb = bid; vb < 512u; vb += NB) {
        int sp = (int)(vb & 31u), hd = (int)(vb >> 5);
        loadKV(Kc_l, Vc_l, sp, hd); __syncthreads(); compB(sp, hd);
      }
    }
    ++e; arrive(e); waitb(e);
    // ---- C
    if (pf) { if (bid < 256u) compC((int)(bid & 15u), (int)(bid >> 4)); }
    else { for (unsigned vb = bid; vb < 256u; vb += NB) compC((int)(vb & 15u), (int)(vb >> 4)); }
    ++e; arrive(e);
    if (pf) pfD(Wg_l, Wu_l, (int)(bid & 31u), (int)(bid >> 5));
    waitb(e);
    // ---- D
    if (pf) compD((int)(bid & 31u), (int)(bid >> 5));
    else {
      for (unsigned vb = bid; vb < 512u; vb += NB) {
        int bx = (int)(vb & 31u), by = (int)(vb >> 5);
        pfD(Wg_l, Wu_l, bx, by); compD(bx, by);
      }
    }
    ++e; arrive(e);
    if (pf && bid >= 256u) pfE(Wd_l, (int)((bid - 256u) & 3u), (int)((bid - 256u) >> 2));
    waitb(e);
    // ---- E
    if (pf) { if (bid >= 256u) compE((int)((bid - 256u) & 3u), (int)((bid - 256u) >> 2)); }
    else {
      for (unsigned vb = bid; vb < 256u; vb += NB) {
        int bx = (int)(vb & 3u), by = (int)(vb >> 2);
        pfE(Wd_l, bx, by); compE(bx, by);
      }
    }
    ++e; arrive(e);
    if (pf && bid < 192u && l < 23) {
      pfA(Wq_l + 1048576, Wk_l + 1048576, Wv_l + 1048576,
          (int)(bid % 12u), (int)(bid / 12u));
    }
    waitb(e);
  }

  // =================== heads ===================
  auto do_stage = [&](int s, int ny, int n3,
                      const float* w1, const float* b1,
                      const float* w2, const float* b2,
                      const float* w3, const float* b3,
                      float* logits, const float* gb) {
    // g1: [res|embs] @ w1 -> gup partials (LNf computed inline for res rows)
    for (unsigned vb = bid; vb < (unsigned)(4 * ny); vb += NB) {
      int bx = (int)(vb & 3u), by = (int)(vb >> 2);
      __syncthreads();
      float mean, rs;
      ln_stats(p.hA, red4, mean, rs);
      if (vb == 0 && tid < n3) logits[tid] = b3[tid];
      int rb = by * 64;
      if (tid < 64) {
        int r = rb + tid;
        xs[tid] = (r < 1024) ? (p.hA[r] - mean) * rs * p.lnfg[r] : p.catE[r - 1024];
      }
      __syncthreads();
      int c4 = tid & 63, w = tid >> 6, r0 = w * 16;
      int vcol4 = bx * 64 + c4;
      const float4* W4 = (const float4*)w1;
      float4 acc = {0.f, 0.f, 0.f, 0.f};
      #pragma unroll
      for (int i = 0; i < 16; ++i) {
        float xv = xs[r0 + i];
        float4 wv = W4[(size_t)(rb + r0 + i) * 256 + vcol4];
        acc.x += xv * wv.x; acc.y += xv * wv.y; acc.z += xv * wv.z; acc.w += xv * wv.w;
      }
      sh4[tid] = acc;
      __syncthreads();
      if (tid < 64) {
        float4 a = sh4[tid], b_ = sh4[tid + 64], c = sh4[tid + 128], d = sh4[tid + 192];
        a.x += b_.x + c.x + d.x; a.y += b_.y + c.y + d.y;
        a.z += b_.z + c.z + d.z; a.w += b_.w + c.w + d.w;
        ((float4*)p.gup)[(size_t)by * 256 + bx * 64 + tid] = a;
      }
    }
    ++e; arrive(e); waitb(e);
    // g2: relu(b1 + sum t1p) @ w2 -> t2p partials
    for (unsigned vb = bid; vb < 64u; vb += NB) {
      int bx = (int)(vb & 3u), by = (int)(vb >> 2);
      __syncthreads();
      int rb = by * 64;
      if (tid < 64) {
        float ssum = b1[rb + tid];
        for (int q = 0; q < ny; ++q) ssum += p.gup[q * 1024 + rb + tid];
        xs[tid] = fmaxf(ssum, 0.f);
      }
      __syncthreads();
      int c4 = tid & 63, w = tid >> 6, r0 = w * 16;
      int vcol4 = bx * 64 + c4;
      const float4* W4 = (const float4*)w2;
      float4 acc = {0.f, 0.f, 0.f, 0.f};
      #pragma unroll
      for (int i = 0; i < 16; ++i) {
        float xv = xs[r0 + i];
        float4 wv = W4[(size_t)(rb + r0 + i) * 256 + vcol4];
        acc.x += xv * wv.x; acc.y += xv * wv.y; acc.z += xv * wv.z; acc.w += xv * wv.w;
      }
      sh4[tid] = acc;
      __syncthreads();
      if (tid < 64) {
        float4 a = sh4[tid], b_ = sh4[tid + 64], c = sh4[tid + 128], d = sh4[tid + 192];
        a.x += b_.x + c.x + d.x; a.y += b_.y + c.y + d.y;
        a.z += b_.z + c.z + d.z; a.w += b_.w + c.w + d.w;
        ((float4*)p.t2p)[(size_t)by * 256 + bx * 64 + tid] = a;
      }
    }
    ++e; arrive(e); waitb(e);
    // g3: relu(b2 + sum t2p) @ w3 -> atomic logits
    for (unsigned vb = bid; vb < 16u; vb += NB) {
      __syncthreads();
      int rb = (int)vb * 64;
      if (tid < 64) {
        float ssum = b2[rb + tid];
        #pragma unroll
        for (int q = 0; q < 16; ++q) ssum += p.t2p[q * 1024 + rb + tid];
        xs[tid] = fmaxf(ssum, 0.f);
      }
      __syncthreads();
      if (tid < n3) {
        float acc = 0.f;
        for (int i = 0; i < 64; ++i) acc += xs[i] * w3[(size_t)(rb + i) * n3 + tid];
        atomicAdd(&logits[tid], acc);
      }
    }
    ++e; arrive(e); waitb(e);
    // sample (block 0)
    if (bid == 0) {
      if (tid == 0) {
        float pr[130];
        float mx = -1e30f;
        for (int i = 0; i < n3; ++i) mx = fmaxf(mx, logits[i]);
        float ssum = 0.f;
        for (int i = 0; i < n3; ++i) { pr[i] = expf(logits[i] - mx); ssum += pr[i]; }
        for (int i = 0; i < n3; ++i) pr[i] /= ssum;
        float tp[10]; int ti[10];
        for (int k = 0; k < 10; ++k) {
          float best = -1.f; int bi = 0;
          for (int i = 0; i < n3; ++i)
            if (pr[i] > best) { best = pr[i]; bi = i; }
          tp[k] = best; ti[k] = bi; pr[bi] = -2.f;
        }
        int choice;
        if (s == 0) {
          int is_eos = (ti[0] == kEOS);
          float mp[10]; float msum = 0.f;
          for (int k = 0; k < 10; ++k) {
            mp[k] = tp[k] * ((ti[k] != kEOS) ? 1.f : 0.f);
            msum += mp[k];
          }
          float bestsc = -1e30f; int ba = 0;
          for (int k = 0; k < 10; ++k) {
            float scv = logf(mp[k] / msum + 1e-9f) + gb[k];
            if (scv > bestsc) { bestsc = scv; ba = k; }
          }
          choice = is_eos ? kEOS : ti[ba];
          p.out[2] = (float)choice;
        } else {
          float bestsc = -1e30f; int ba = 0;
          for (int k = 0; k < 10; ++k) {
            float scv = logf(tp[k] + 1e-9f) + gb[k];
            if (scv > bestsc) { bestsc = scv; ba = k; }
          }
          choice = ti[ba];
          if (s == 1) p.out[1] = (float)choice;
          else        p.out[0] = (float)choice;
        }
        ish = choice;
      }
      __syncthreads();
      if (s == 0) {
        int zi = ish; if (zi > 127) zi = 127;
        for (int i = tid; i < 1024; i += 256)
          p.catE[i] = p.c1emb[(size_t)zi * 1024 + i];
      } else if (s == 1) {
        int y = ish;
        for (int i = tid; i < 1024; i += 256)
          p.catE[1024 + i] = p.c2emb[(size_t)y * 1024 + i];
      }
    }
    ++e; arrive(e); waitb(e);
  };

  do_stage(0, 16, 130, p.h1w1, p.h1b1, p.h1w2, p.h1b2, p.h1w3, p.h1b3, p.out + 3,   p.G);
  do_stage(1, 32, 128, p.h2w1, p.h2b1, p.h2w2, p.h2b2, p.h2w3, p.h2b3, p.out + 133, p.G + 10);
  do_stage(2, 48, 128, p.h3w1, p.h3b1, p.h3w2, p.h3b2, p.h3w3, p.h3b3, p.out + 261, p.G + 20);
}

// ---------------- host: JAX threefry2x32 (partitionable) ----------------

static inline uint32_t rotl32(uint32_t x, uint32_t r) { return (x << r) | (x >> (32 - r)); }

static void threefry2x32(uint32_t k0, uint32_t k1, uint32_t x0, uint32_t x1,
                         uint32_t* o0, uint32_t* o1) {
  uint32_t ks0 = k0, ks1 = k1, ks2 = k0 ^ k1 ^ 0x1BD11BDAu;
  const uint32_t R0[4] = {13, 15, 26, 6};
  const uint32_t R1[4] = {17, 29, 16, 24};
  x0 += ks0; x1 += ks1;
  for (int j = 0; j < 4; ++j) { x0 += x1; x1 = rotl32(x1, R0[j]); x1 ^= x0; }
  x0 += ks1; x1 += ks2 + 1u;
  for (int j = 0; j < 4; ++j) { x0 += x1; x1 = rotl32(x1, R1[j]); x1 ^= x0; }
  x0 += ks2; x1 += ks0 + 2u;
  for (int j = 0; j < 4; ++j) { x0 += x1; x1 = rotl32(x1, R0[j]); x1 ^= x0; }
  x0 += ks0; x1 += ks1 + 3u;
  for (int j = 0; j < 4; ++j) { x0 += x1; x1 = rotl32(x1, R1[j]); x1 ^= x0; }
  x0 += ks1; x1 += ks2 + 4u;
  for (int j = 0; j < 4; ++j) { x0 += x1; x1 = rotl32(x1, R0[j]); x1 ^= x0; }
  x0 += ks2; x1 += ks0 + 5u;
  *o0 = x0; *o1 = x1;
}

static void gumbel10_part(uint32_t k0, uint32_t k1, float* g) {
  const float tiny = 1.1754943508222875e-38f;
  for (int i = 0; i < 10; ++i) {
    uint32_t a, c;
    threefry2x32(k0, k1, 0u, (uint32_t)i, &a, &c);
    uint32_t bits = a ^ c;
    uint32_t fb = (bits >> 9) | 0x3f800000u;
    float f; memcpy(&f, &fb, 4);
    f -= 1.0f;
    float u = f * (1.0f - tiny) + tiny;
    if (u < tiny) u = tiny;
    g[i] = -logf(-logf(u));
  }
}

// ---------------- entry ----------------

extern "C" void kernel_launch(void* const* d_in, const int* in_sizes, int n_in,
                              void* d_out, int out_size, void* d_ws, size_t ws_size,
                              hipStream_t stream) {
  (void)in_sizes; (void)n_in; (void)out_size; (void)ws_size;
  float* ws = (float*)d_ws;

  Params prm;
  prm.x    = (const float*)d_in[0];
  prm.kc   = (const float*)d_in[1];
  prm.vc   = (const float*)d_in[2];
  prm.ln1g = (const float*)d_in[3];
  prm.Wq   = (const float*)d_in[4];
  prm.Wk   = (const float*)d_in[5];
  prm.Wv   = (const float*)d_in[6];
  prm.Wo   = (const float*)d_in[7];
  prm.ln2g = (const float*)d_in[8];
  prm.Wg   = (const float*)d_in[9];
  prm.Wu   = (const float*)d_in[10];
  prm.Wd   = (const float*)d_in[11];
  prm.lnfg = (const float*)d_in[12];
  prm.h1w1 = (const float*)d_in[13]; prm.h1b1 = (const float*)d_in[14];
  prm.h1w2 = (const float*)d_in[15]; prm.h1b2 = (const float*)d_in[16];
  prm.h1w3 = (const float*)d_in[17]; prm.h1b3 = (const float*)d_in[18];
  prm.h2w1 = (const float*)d_in[19]; prm.h2b1 = (const float*)d_in[20];
  prm.h2w2 = (const float*)d_in[21]; prm.h2b2 = (const float*)d_in[22];
  prm.h2w3 = (const float*)d_in[23]; prm.h2b3 = (const float*)d_in[24];
  prm.h3w1 = (const float*)d_in[25]; prm.h3b1 = (const float*)d_in[26];
  prm.h3w2 = (const float*)d_in[27]; prm.h3b2 = (const float*)d_in[28];
  prm.h3w3 = (const float*)d_in[29]; prm.h3b3 = (const float*)d_in[30];
  prm.c1emb = (const float*)d_in[31];
  prm.c2emb = (const float*)d_in[32];

  prm.hA   = ws;                    // 1024
  prm.hB   = ws + 1024;             // 1024
  prm.qkvp = ws + 2048;             // 16*3072 = 49152
  prm.part = ws + 51200;            // 16*32*68 = 34816
  prm.gup  = ws + 86016;            // 16*8192 = 131072 (t1p alias in heads)
  prm.t2p  = ws + 217088;           // 16*1024 = 16384
  prm.catE = ws + 233472;           // 2048 (emb_z | emb_y)
  prm.out  = (float*)d_out;
  prm.bar  = (unsigned*)(ws + 235520);  // 2592 uints

  uint32_t k1a, k1b, k2a, k2b, k3a, k3b;
  threefry2x32(0u, 42u, 0u, 0u, &k1a, &k1b);
  threefry2x32(0u, 42u, 0u, 1u, &k2a, &k2b);
  threefry2x32(0u, 42u, 0u, 2u, &k3a, &k3b);
  gumbel10_part(k1a, k1b, prm.G);
  gumbel10_part(k2a, k2b, prm.G + 10);
  gumbel10_part(k3a, k3b, prm.G + 20);

  hipMemsetAsync(prm.bar, 0, 2592 * sizeof(unsigned), stream);

  static int occ = -1;
  if (occ < 0) {
    int nb = 0;
    if (hipOccupancyMaxActiveBlocksPerMultiprocessor(&nb, k_all, 256, 0) != hipSuccess || nb < 1)
      nb = 1;
    occ = nb;
  }
  int nblk = (occ >= 2) ? 512 : 256;

  void* args[] = { &prm };
  hipLaunchCooperativeKernel(k_all, dim3(nblk), dim3(256), args, 0, stream);
}